// Round 7
// baseline (392.694 us; speedup 1.0000x reference)
//
#include <hip/hip_runtime.h>
#include <hip/hip_bf16.h>

#define NN 50000
#define EE 800000
#define ET (NN + EE)   // edges incl. self-loops = 850000
#define SG ((NN + 255) / 256)   // scan blocks = 196

typedef __attribute__((ext_vector_type(8))) short short8;
typedef __attribute__((ext_vector_type(4))) float f32x4;

__device__ __forceinline__ float bf2f(unsigned short u) {
    union { unsigned int i; float f; } v; v.i = ((unsigned int)u) << 16; return v.f;
}
__device__ __forceinline__ unsigned short f2bf(float f) {
    __hip_bfloat16 h = __float2bfloat16(f);
    return *reinterpret_cast<unsigned short*>(&h);
}
__device__ __forceinline__ float lrelu(float e) { return e > 0.f ? e : 0.2f * e; }

// ---------------- CSR build ----------------

__global__ void k_init_cnt(int* __restrict__ cnt) {
    int i = blockIdx.x * blockDim.x + threadIdx.x;
    if (i < NN) cnt[i] = 1;   // self-loop pre-counted
}

__global__ void k_hist(const int* __restrict__ dst, int* __restrict__ cnt) {
    int i = blockIdx.x * blockDim.x + threadIdx.x;
    if (i < EE) atomicAdd(&cnt[dst[i]], 1);
}

__global__ __launch_bounds__(256) void k_scan1(const int* __restrict__ cnt,
                                               int* __restrict__ tmp, int* __restrict__ bsum) {
    int b = blockIdx.x, t = threadIdx.x, i = b * 256 + t;
    int lane = t & 63, w = t >> 6;
    int v = (i < NN) ? cnt[i] : 0;
    int s = v;
    #pragma unroll
    for (int off = 1; off < 64; off <<= 1) {
        int u = __shfl_up(s, off);
        if (lane >= off) s += u;
    }
    __shared__ int ws[4];
    if (lane == 63) ws[w] = s;
    __syncthreads();
    if (t == 0) {
        int a = 0;
        #pragma unroll
        for (int k = 0; k < 4; k++) { int x = ws[k]; ws[k] = a; a += x; }
        bsum[b] = a;
    }
    __syncthreads();
    s += ws[w];
    if (i < NN) tmp[i] = s;   // inclusive within block
}

__global__ __launch_bounds__(256) void k_scan2(const int* __restrict__ bsum, int* __restrict__ boff) {
    int t = threadIdx.x, lane = t & 63, w = t >> 6;
    int v = (t < SG) ? bsum[t] : 0;
    int s = v;
    #pragma unroll
    for (int off = 1; off < 64; off <<= 1) {
        int u = __shfl_up(s, off);
        if (lane >= off) s += u;
    }
    __shared__ int ws[4];
    if (lane == 63) ws[w] = s;
    __syncthreads();
    if (t == 0) {
        int a = 0;
        #pragma unroll
        for (int k = 0; k < 4; k++) { int x = ws[k]; ws[k] = a; a += x; }
    }
    __syncthreads();
    s += ws[w];
    if (t < SG) boff[t] = s - v;   // exclusive
}

__global__ void k_scan3_prep(const int* __restrict__ tmp, const int* __restrict__ boff,
                             int* __restrict__ rowptr, int* __restrict__ writeptr,
                             int* __restrict__ csr, int* __restrict__ dstarr) {
    int i = blockIdx.x * blockDim.x + threadIdx.x;
    if (i == 0) rowptr[0] = 0;
    if (i < NN) {
        int incl = tmp[i] + boff[i >> 8];
        rowptr[i + 1] = incl;
        int v = (i & 255) ? tmp[i - 1] + boff[i >> 8] : boff[i >> 8];  // exclusive = rowptr[i]
        csr[v] = i;            // self-loop first
        dstarr[v] = i;
        writeptr[i] = v + 1;
    }
}

__global__ void k_scatter(const int* __restrict__ src, const int* __restrict__ dst,
                          int* __restrict__ writeptr, int* __restrict__ csr,
                          int* __restrict__ dstarr) {
    int i = blockIdx.x * blockDim.x + threadIdx.x;
    if (i < EE) {
        int d = dst[i];
        int pos = atomicAdd(&writeptr[d], 1);
        csr[pos] = src[i];
        dstarr[pos] = d;
    }
}

// ---------------- MFMA bf16 GEMM with fused attention-score epilogue ----------------
template<int K, int N, int NH, bool A_BF16>
__global__ __launch_bounds__(256) void k_gemm_mfma(
    const void* __restrict__ Aptr, const float* __restrict__ W,
    const float* __restrict__ atts, const float* __restrict__ attd,
    unsigned short* __restrict__ C, float* __restrict__ as_, float* __restrict__ ad_,
    int M)
{
    constexpr int KU  = K / 8;        // 16B units per row
    constexpr int KUH = KU / 2;       // units per K-half
    constexpr int KC  = K / 32;       // mfma K-chunks
    constexpr int NW  = N / 4;        // cols per wave
    constexpr int NI  = NW / 16;      // 16-col tiles per wave
    constexpr int ABYTES = 64 * KU * 16;
    constexpr int BBYTES = N * KUH * 16;
    constexpr int SMEM = ABYTES + BBYTES + (NH == 1 ? 2048 : 0);
    __shared__ char smem[SMEM];
    char* Ash = smem;
    char* Bsh = smem + ABYTES;
    unsigned short* Csh = (unsigned short*)smem;          // overlay after compute
    float* scsh = (float*)(smem + ABYTES + BBYTES);       // NH==1 only

    int t = threadIdx.x;
    int lane = t & 63, w = t >> 6;
    int colL = lane & 15, quad = lane >> 4;
    int m0 = blockIdx.x * 64;

    // ---- stage A (full K) ----
    {
        constexpr int CNT = 64 * KU / 256;
        #pragma unroll
        for (int i = 0; i < CNT; i++) {
            int v = t + 256 * i;
            int m = v / KU, u = v % KU;
            int gr = m0 + m; if (gr >= M) gr = M - 1;
            short8 val;
            if (A_BF16) {
                val = *(const short8*)((const unsigned short*)Aptr + (size_t)gr * K + u * 8);
            } else {
                const float* Af = (const float*)Aptr;
                float4 lo = *(const float4*)(Af + (size_t)gr * K + u * 8);
                float4 hi = *(const float4*)(Af + (size_t)gr * K + u * 8 + 4);
                val[0] = (short)f2bf(lo.x); val[1] = (short)f2bf(lo.y);
                val[2] = (short)f2bf(lo.z); val[3] = (short)f2bf(lo.w);
                val[4] = (short)f2bf(hi.x); val[5] = (short)f2bf(hi.y);
                val[6] = (short)f2bf(hi.z); val[7] = (short)f2bf(hi.w);
            }
            *(short8*)(Ash + ((size_t)m * KU + (u ^ (m & 7))) * 16) = val;
        }
    }

    f32x4 acc[4][NI];
    #pragma unroll
    for (int mi = 0; mi < 4; mi++)
        #pragma unroll
        for (int ni = 0; ni < NI; ni++) acc[mi][ni] = (f32x4){0.f, 0.f, 0.f, 0.f};

    #pragma unroll
    for (int kh = 0; kh < 2; kh++) {
        __syncthreads();
        // ---- stage B half ----
        {
            constexpr int CNT = N * KUH / 256;
            #pragma unroll
            for (int i = 0; i < CNT; i++) {
                int v = t + 256 * i;
                int n = v / KUH, uu = v % KUH;
                int u = kh * KUH + uu;
                float4 lo = *(const float4*)(W + (size_t)n * K + u * 8);
                float4 hi = *(const float4*)(W + (size_t)n * K + u * 8 + 4);
                short8 val;
                val[0] = (short)f2bf(lo.x); val[1] = (short)f2bf(lo.y);
                val[2] = (short)f2bf(lo.z); val[3] = (short)f2bf(lo.w);
                val[4] = (short)f2bf(hi.x); val[5] = (short)f2bf(hi.y);
                val[6] = (short)f2bf(hi.z); val[7] = (short)f2bf(hi.w);
                *(short8*)(Bsh + ((size_t)n * KUH + (uu ^ (n & 7))) * 16) = val;
            }
        }
        __syncthreads();
        #pragma unroll
        for (int kcl = 0; kcl < KC / 2; kcl++) {
            int uA = (kh * (KC / 2) + kcl) * 4 + quad;
            int uB = kcl * 4 + quad;
            short8 bf[NI];
            #pragma unroll
            for (int ni = 0; ni < NI; ni++) {
                int n = w * NW + ni * 16 + colL;
                bf[ni] = *(const short8*)(Bsh + ((size_t)n * KUH + (uB ^ (n & 7))) * 16);
            }
            #pragma unroll
            for (int mi = 0; mi < 4; mi++) {
                int m = mi * 16 + colL;
                short8 af = *(const short8*)(Ash + ((size_t)m * KU + (uA ^ (m & 7))) * 16);
                #pragma unroll
                for (int ni = 0; ni < NI; ni++)
                    acc[mi][ni] = __builtin_amdgcn_mfma_f32_16x16x32_bf16(af, bf[ni], acc[mi][ni], 0, 0, 0);
            }
        }
    }
    __syncthreads();   // all LDS reads done; Csh/scsh overlay safe

    // ---- attention scores ----
    float asv[NI], adv[NI];
    #pragma unroll
    for (int ni = 0; ni < NI; ni++) {
        int na = (NH == 4) ? (w * 64 + ni * 16 + colL) : (w * 16 + colL);
        asv[ni] = atts[na];
        adv[ni] = attd[na];
    }
    #pragma unroll
    for (int mi = 0; mi < 4; mi++) {
        float ps[4] = {0.f, 0.f, 0.f, 0.f}, pd[4] = {0.f, 0.f, 0.f, 0.f};
        #pragma unroll
        for (int ni = 0; ni < NI; ni++)
            #pragma unroll
            for (int r = 0; r < 4; r++) {
                ps[r] += acc[mi][ni][r] * asv[ni];
                pd[r] += acc[mi][ni][r] * adv[ni];
            }
        #pragma unroll
        for (int off = 1; off < 16; off <<= 1)
            #pragma unroll
            for (int r = 0; r < 4; r++) {
                ps[r] += __shfl_xor(ps[r], off);
                pd[r] += __shfl_xor(pd[r], off);
            }
        if (colL == 0) {
            #pragma unroll
            for (int r = 0; r < 4; r++) {
                int rloc = mi * 16 + quad * 4 + r;
                if (NH == 4) {
                    int row = m0 + rloc;
                    if (row < M) {
                        as_[(size_t)row * 4 + w] = ps[r];
                        ad_[(size_t)row * 4 + w] = pd[r];
                    }
                } else {
                    scsh[(w * 64 + rloc) * 2 + 0] = ps[r];
                    scsh[(w * 64 + rloc) * 2 + 1] = pd[r];
                }
            }
        }
    }

    // ---- C repack to LDS (bf16) ----
    #pragma unroll
    for (int mi = 0; mi < 4; mi++)
        #pragma unroll
        for (int ni = 0; ni < NI; ni++)
            #pragma unroll
            for (int r = 0; r < 4; r++)
                Csh[(size_t)(mi * 16 + quad * 4 + r) * (N + 8) + w * NW + ni * 16 + colL] =
                    f2bf(acc[mi][ni][r]);
    __syncthreads();

    // ---- coalesced global store ----
    {
        constexpr int CNT = 64 * (N / 8) / 256;
        #pragma unroll
        for (int i = 0; i < CNT; i++) {
            int v = t + 256 * i;
            int m = v / (N / 8), u = v % (N / 8);
            int row = m0 + m;
            if (row < M)
                *(short8*)(C + (size_t)row * N + u * 8) =
                    *(const short8*)(Csh + (size_t)m * (N + 8) + u * 8);
        }
    }
    if (NH == 1 && t < 64) {
        int row = m0 + t;
        if (row < M) {
            float s = 0.f, d = 0.f;
            #pragma unroll
            for (int ww = 0; ww < 4; ww++) {
                s += scsh[(ww * 64 + t) * 2 + 0];
                d += scsh[(ww * 64 + t) * 2 + 1];
            }
            as_[row] = s;
            ad_[row] = d;
        }
    }
}

// ---------------- edge-score precompute (edge-parallel, transposed head planes) ----------------
__global__ void k_escore1(const int* __restrict__ csr, const int* __restrict__ dstarr,
                          const float* __restrict__ as1, const float* __restrict__ ad1,
                          float* __restrict__ ewT) {
    int i = blockIdx.x * blockDim.x + threadIdx.x;
    if (i < ET) {
        int s = csr[i], n = dstarr[i];
        float4 a = *(const float4*)(as1 + (size_t)s * 4);
        float4 d = *(const float4*)(ad1 + (size_t)n * 4);
        ewT[0 * (size_t)ET + i] = __expf(lrelu(a.x + d.x));
        ewT[1 * (size_t)ET + i] = __expf(lrelu(a.y + d.y));
        ewT[2 * (size_t)ET + i] = __expf(lrelu(a.z + d.z));
        ewT[3 * (size_t)ET + i] = __expf(lrelu(a.w + d.w));
    }
}

__global__ void k_escore2(const int* __restrict__ csr, const int* __restrict__ dstarr,
                          const float* __restrict__ as2, const float* __restrict__ ad2,
                          float* __restrict__ ew) {
    int i = blockIdx.x * blockDim.x + threadIdx.x;
    if (i < ET) {
        int s = csr[i], n = dstarr[i];
        ew[i] = __expf(lrelu(as2[s] + ad2[n]));
    }
}

// ---------------- Layer-1 aggregation: XCD-sliced channels, 8 edges in flight ----------------
// slice = bid&7 -> 32 channels (3.2 MB of xt1, fits one XCD's 4MB L2 via %8 round-robin).
// Wave handles 4 nodes; per node, 8 edge slots x 8 lanes (ushort4 = 8B each -> 64B/edge).
__global__ __launch_bounds__(256) void k_l1_agg(
    const unsigned short* __restrict__ xt1, const float* __restrict__ ewT,
    const int* __restrict__ rowptr, const int* __restrict__ csr,
    const float* __restrict__ b1, unsigned short* __restrict__ h1)
{
    int t = threadIdx.x;
    int lane = t & 63, w = t >> 6;
    int slice = blockIdx.x & 7;
    int nb = blockIdx.x >> 3;
    int c0 = slice * 32;
    const float* ewp = ewT + (size_t)(slice >> 1) * ET;   // head plane
    int q = lane >> 3;       // edge slot 0..7
    int cl = lane & 7;       // channel quad within slice

    float4 bv = *(const float4*)(b1 + c0 + cl * 4);

    #pragma unroll
    for (int rep = 0; rep < 4; rep++) {
        int n = nb * 16 + w + rep * 4;           // 16 nodes per block
        int beg = rowptr[n], end = rowptr[n + 1];
        float a0 = 0.f, a1 = 0.f, a2 = 0.f, a3 = 0.f, esum = 0.f;
        for (int p0 = beg; p0 < end; p0 += 8) {
            int p = p0 + q;
            int pc = min(p, end - 1);
            int s = csr[pc];
            float e = ewp[pc];
            if (p >= end) e = 0.f;
            ushort4 r = *(const ushort4*)(xt1 + (size_t)s * 256 + c0 + cl * 4);
            esum += e;
            a0 += bf2f(r.x) * e;
            a1 += bf2f(r.y) * e;
            a2 += bf2f(r.z) * e;
            a3 += bf2f(r.w) * e;
        }
        // reduce across 8 edge slots (lane bits 3,4,5)
        #pragma unroll
        for (int off = 8; off < 64; off <<= 1) {
            a0 += __shfl_xor(a0, off);
            a1 += __shfl_xor(a1, off);
            a2 += __shfl_xor(a2, off);
            a3 += __shfl_xor(a3, off);
            esum += __shfl_xor(esum, off);
        }
        if (q == 0) {
            float rs = 1.f / (esum + 1e-16f);
            ushort4 o;
            o.x = f2bf(fmaxf(a0 * rs + bv.x, 0.f));
            o.y = f2bf(fmaxf(a1 * rs + bv.y, 0.f));
            o.z = f2bf(fmaxf(a2 * rs + bv.z, 0.f));
            o.w = f2bf(fmaxf(a3 * rs + bv.w, 0.f));
            *(ushort4*)(h1 + (size_t)n * 256 + c0 + cl * 4) = o;
        }
    }
}

// ---------------- Layer-2 aggregation + fc + sigmoid: wave/node, 8-deep ----------------
__global__ __launch_bounds__(256) void k_l2_agg(
    const unsigned short* __restrict__ xt2, const float* __restrict__ ew,
    const int* __restrict__ rowptr, const int* __restrict__ csr,
    const float* __restrict__ b2, const float* __restrict__ fcw, const float* __restrict__ fcb,
    float* __restrict__ out)
{
    int t = threadIdx.x;
    int lane = t & 63, w = t >> 6;
    int n = blockIdx.x * 4 + w;
    int beg = rowptr[n], deg = rowptr[n + 1] - beg;
    int half = lane >> 5, c = lane & 31;   // lane owns channels 2c, 2c+1

    float a0 = 0.f, a1 = 0.f, esum = 0.f;
    int j = 0;
    for (; j + 8 <= deg; j += 8) {
        int p = beg + j + half * 4;
        int s0 = csr[p], s1 = csr[p + 1], s2 = csr[p + 2], s3 = csr[p + 3];
        float e0 = ew[p], e1 = ew[p + 1], e2 = ew[p + 2], e3 = ew[p + 3];
        unsigned int r0 = *(const unsigned int*)(xt2 + (size_t)s0 * 64 + c * 2);
        unsigned int r1 = *(const unsigned int*)(xt2 + (size_t)s1 * 64 + c * 2);
        unsigned int r2 = *(const unsigned int*)(xt2 + (size_t)s2 * 64 + c * 2);
        unsigned int r3 = *(const unsigned int*)(xt2 + (size_t)s3 * 64 + c * 2);
        esum += (e0 + e1) + (e2 + e3);
        a0 += bf2f(r0 & 0xffff) * e0 + bf2f(r1 & 0xffff) * e1
            + bf2f(r2 & 0xffff) * e2 + bf2f(r3 & 0xffff) * e3;
        a1 += bf2f(r0 >> 16) * e0 + bf2f(r1 >> 16) * e1
            + bf2f(r2 >> 16) * e2 + bf2f(r3 >> 16) * e3;
    }
    for (; j < deg; j += 2) {
        int jj = j + half;
        if (jj < deg) {
            int p = beg + jj;
            int s = csr[p];
            float e = ew[p];
            unsigned int r = *(const unsigned int*)(xt2 + (size_t)s * 64 + c * 2);
            esum += e;
            a0 += bf2f(r & 0xffff) * e;
            a1 += bf2f(r >> 16) * e;
        }
    }
    a0 += __shfl_xor(a0, 32);
    a1 += __shfl_xor(a1, 32);
    esum += __shfl_xor(esum, 32);
    if (half == 0) {
        float rs = 1.f / (esum + 1e-16f);
        float o0 = fmaxf(a0 * rs + b2[c * 2], 0.f);
        float o1 = fmaxf(a1 * rs + b2[c * 2 + 1], 0.f);
        float z = o0 * fcw[c * 2] + o1 * fcw[c * 2 + 1];
        #pragma unroll
        for (int off = 16; off; off >>= 1) z += __shfl_xor(z, off);
        if (c == 0) out[n] = 1.f / (1.f + __expf(-(z + fcb[0])));
    }
}

// ---------------- launch ----------------

extern "C" void kernel_launch(void* const* d_in, const int* in_sizes, int n_in,
                              void* d_out, int out_size, void* d_ws, size_t ws_size,
                              hipStream_t stream) {
    const float* x    = (const float*)d_in[0];
    const int*   ei   = (const int*)d_in[1];
    const float* W1   = (const float*)d_in[2];
    const float* as1w = (const float*)d_in[3];
    const float* ad1w = (const float*)d_in[4];
    const float* b1   = (const float*)d_in[5];
    const float* W2   = (const float*)d_in[6];
    const float* as2w = (const float*)d_in[7];
    const float* ad2w = (const float*)d_in[8];
    const float* b2   = (const float*)d_in[9];
    const float* fcw  = (const float*)d_in[10];
    const float* fcb  = (const float*)d_in[11];
    float* out = (float*)d_out;

    const int* src = ei;
    const int* dst = ei + EE;

    char* base = (char*)d_ws;
    size_t off = 0;
    auto alloc = [&](size_t bytes) -> void* {
        void* p = base + off;
        off = (off + bytes + 255) & ~(size_t)255;
        return p;
    };
    int*   rowptr   = (int*)alloc((NN + 1) * sizeof(int));
    int*   cnt      = (int*)alloc(NN * sizeof(int));
    int*   tmp      = (int*)alloc(NN * sizeof(int));
    int*   bsum     = (int*)alloc(SG * sizeof(int));
    int*   boff     = (int*)alloc(SG * sizeof(int));
    int*   writeptr = (int*)alloc(NN * sizeof(int));
    int*   csr      = (int*)alloc(ET * sizeof(int));
    int*   dstarr   = (int*)alloc(ET * sizeof(int));
    float* ewT      = (float*)alloc((size_t)ET * 4 * sizeof(float));   // 4 head planes
    unsigned short* xt1 = (unsigned short*)alloc((size_t)NN * 256 * sizeof(unsigned short));
    unsigned short* h1  = (unsigned short*)alloc((size_t)NN * 256 * sizeof(unsigned short));
    float* as1      = (float*)alloc(NN * 4 * sizeof(float));
    float* ad1      = (float*)alloc(NN * 4 * sizeof(float));
    float* as2      = (float*)alloc(NN * sizeof(float));
    float* ad2      = (float*)alloc(NN * sizeof(float));
    unsigned short* xt2 = xt1;   // xt1 dead after l1_agg; reuse
    float* ew2      = ewT;       // plane-0 region reused flat for layer 2

    // CSR build (parallel scan)
    k_init_cnt<<<(NN + 255) / 256, 256, 0, stream>>>(cnt);
    k_hist<<<(EE + 255) / 256, 256, 0, stream>>>(dst, cnt);
    k_scan1<<<SG, 256, 0, stream>>>(cnt, tmp, bsum);
    k_scan2<<<1, 256, 0, stream>>>(bsum, boff);
    k_scan3_prep<<<SG, 256, 0, stream>>>(tmp, boff, rowptr, writeptr, csr, dstarr);
    k_scatter<<<(EE + 255) / 256, 256, 0, stream>>>(src, dst, writeptr, csr, dstarr);

    int gblocks = (NN + 63) / 64;  // 782
    k_gemm_mfma<128, 256, 4, false><<<gblocks, 256, 0, stream>>>(
        x, W1, as1w, ad1w, xt1, as1, ad1, NN);
    k_escore1<<<(ET + 255) / 256, 256, 0, stream>>>(csr, dstarr, as1, ad1, ewT);
    k_l1_agg<<<8 * (NN / 16), 256, 0, stream>>>(xt1, ewT, rowptr, csr, b1, h1);  // 50000%16==0
    k_gemm_mfma<256, 64, 1, true><<<gblocks, 256, 0, stream>>>(
        h1, W2, as2w, ad2w, xt2, as2, ad2, NN);
    k_escore2<<<(ET + 255) / 256, 256, 0, stream>>>(csr, dstarr, as2, ad2, ew2);
    k_l2_agg<<<(NN + 3) / 4, 256, 0, stream>>>(xt2, ew2, rowptr, csr, b2, fcw, fcb, out);
}

// Round 8
// 289.861 us; speedup vs baseline: 1.3548x; 1.3548x over previous
//
#include <hip/hip_runtime.h>
#include <hip/hip_bf16.h>

#define NN 50000
#define EE 800000
#define ET (NN + EE)   // edges incl. self-loops = 850000
#define SG ((NN + 255) / 256)   // scan blocks = 196
#define GB1 ((NN + 63) / 64)    // gemm1 blocks = 782

typedef __attribute__((ext_vector_type(8))) short short8;
typedef __attribute__((ext_vector_type(4))) float f32x4;

__device__ __forceinline__ float bf2f(unsigned short u) {
    union { unsigned int i; float f; } v; v.i = ((unsigned int)u) << 16; return v.f;
}
__device__ __forceinline__ unsigned short f2bf(float f) {
    __hip_bfloat16 h = __float2bfloat16(f);
    return *reinterpret_cast<unsigned short*>(&h);
}
__device__ __forceinline__ float lrelu(float e) { return e > 0.f ? e : 0.2f * e; }

// ---------------- CSR build ----------------
// cnt starts 0 (memset); self-loop handled as "+i" in scan3 arithmetic.

__global__ void k_hist(const int* __restrict__ dst, int* __restrict__ cnt) {
    int i = blockIdx.x * blockDim.x + threadIdx.x;
    if (i < EE) atomicAdd(&cnt[dst[i]], 1);
}

__global__ __launch_bounds__(256) void k_scan1(const int* __restrict__ cnt,
                                               int* __restrict__ tmp, int* __restrict__ bsum) {
    int b = blockIdx.x, t = threadIdx.x, i = b * 256 + t;
    int lane = t & 63, w = t >> 6;
    int v = (i < NN) ? cnt[i] : 0;
    int s = v;
    #pragma unroll
    for (int off = 1; off < 64; off <<= 1) {
        int u = __shfl_up(s, off);
        if (lane >= off) s += u;
    }
    __shared__ int ws[4];
    if (lane == 63) ws[w] = s;
    __syncthreads();
    if (t == 0) {
        int a = 0;
        #pragma unroll
        for (int k = 0; k < 4; k++) { int x = ws[k]; ws[k] = a; a += x; }
        bsum[b] = a;
    }
    __syncthreads();
    s += ws[w];
    if (i < NN) tmp[i] = s;   // inclusive within block (edge counts only)
}

__global__ __launch_bounds__(256) void k_scan2(const int* __restrict__ bsum, int* __restrict__ boff) {
    int t = threadIdx.x, lane = t & 63, w = t >> 6;
    int v = (t < SG) ? bsum[t] : 0;
    int s = v;
    #pragma unroll
    for (int off = 1; off < 64; off <<= 1) {
        int u = __shfl_up(s, off);
        if (lane >= off) s += u;
    }
    __shared__ int ws[4];
    if (lane == 63) ws[w] = s;
    __syncthreads();
    if (t == 0) {
        int a = 0;
        #pragma unroll
        for (int k = 0; k < 4; k++) { int x = ws[k]; ws[k] = a; a += x; }
    }
    __syncthreads();
    s += ws[w];
    if (t < SG) boff[t] = s - v;   // exclusive
}

// rowptr[i+1] = scan(cnt)[i] + (i+1)  (the +i+1 accounts for one self-loop per node)
__global__ void k_scan3_prep(const int* __restrict__ tmp, const int* __restrict__ boff,
                             int* __restrict__ rowptr, int* __restrict__ writeptr,
                             int* __restrict__ csr) {
    int i = blockIdx.x * blockDim.x + threadIdx.x;
    if (i == 0) rowptr[0] = 0;
    if (i < NN) {
        int base = boff[i >> 8];
        int incl = tmp[i] + base + i + 1;
        rowptr[i + 1] = incl;
        int excl = ((i & 255) ? tmp[i - 1] + base : base) + i;   // == rowptr[i]
        csr[excl] = i;            // self-loop first
        writeptr[i] = excl + 1;
    }
}

// ---------------- MFMA bf16 GEMM body (device fn, shared by fused + standalone) ----------------
template<int K, int N, int NH, bool A_BF16>
__device__ __forceinline__ void gemm_body(
    int bid, const void* __restrict__ Aptr, const float* __restrict__ W,
    const float* __restrict__ atts, const float* __restrict__ attd,
    unsigned short* __restrict__ C, float* __restrict__ as_, float* __restrict__ ad_,
    int M)
{
    constexpr int KU  = K / 8;        // 16B units per row
    constexpr int KUH = KU / 2;       // units per K-half
    constexpr int KC  = K / 32;       // mfma K-chunks
    constexpr int NW  = N / 4;        // cols per wave
    constexpr int NI  = NW / 16;      // 16-col tiles per wave
    constexpr int ABYTES = 64 * KU * 16;
    constexpr int BBYTES = N * KUH * 16;
    constexpr int SMEM = ABYTES + BBYTES + (NH == 1 ? 2048 : 0);
    __shared__ char smem[SMEM];
    char* Ash = smem;
    char* Bsh = smem + ABYTES;
    unsigned short* Csh = (unsigned short*)smem;          // overlay after compute
    float* scsh = (float*)(smem + ABYTES + BBYTES);       // NH==1 only

    int t = threadIdx.x;
    int lane = t & 63, w = t >> 6;
    int colL = lane & 15, quad = lane >> 4;
    int m0 = bid * 64;

    // ---- stage A (full K) ----
    {
        constexpr int CNT = 64 * KU / 256;
        #pragma unroll
        for (int i = 0; i < CNT; i++) {
            int v = t + 256 * i;
            int m = v / KU, u = v % KU;
            int gr = m0 + m; if (gr >= M) gr = M - 1;
            short8 val;
            if (A_BF16) {
                val = *(const short8*)((const unsigned short*)Aptr + (size_t)gr * K + u * 8);
            } else {
                const float* Af = (const float*)Aptr;
                float4 lo = *(const float4*)(Af + (size_t)gr * K + u * 8);
                float4 hi = *(const float4*)(Af + (size_t)gr * K + u * 8 + 4);
                val[0] = (short)f2bf(lo.x); val[1] = (short)f2bf(lo.y);
                val[2] = (short)f2bf(lo.z); val[3] = (short)f2bf(lo.w);
                val[4] = (short)f2bf(hi.x); val[5] = (short)f2bf(hi.y);
                val[6] = (short)f2bf(hi.z); val[7] = (short)f2bf(hi.w);
            }
            *(short8*)(Ash + ((size_t)m * KU + (u ^ (m & 7))) * 16) = val;
        }
    }

    f32x4 acc[4][NI];
    #pragma unroll
    for (int mi = 0; mi < 4; mi++)
        #pragma unroll
        for (int ni = 0; ni < NI; ni++) acc[mi][ni] = (f32x4){0.f, 0.f, 0.f, 0.f};

    #pragma unroll
    for (int kh = 0; kh < 2; kh++) {
        __syncthreads();
        // ---- stage B half ----
        {
            constexpr int CNT = N * KUH / 256;
            #pragma unroll
            for (int i = 0; i < CNT; i++) {
                int v = t + 256 * i;
                int n = v / KUH, uu = v % KUH;
                int u = kh * KUH + uu;
                float4 lo = *(const float4*)(W + (size_t)n * K + u * 8);
                float4 hi = *(const float4*)(W + (size_t)n * K + u * 8 + 4);
                short8 val;
                val[0] = (short)f2bf(lo.x); val[1] = (short)f2bf(lo.y);
                val[2] = (short)f2bf(lo.z); val[3] = (short)f2bf(lo.w);
                val[4] = (short)f2bf(hi.x); val[5] = (short)f2bf(hi.y);
                val[6] = (short)f2bf(hi.z); val[7] = (short)f2bf(hi.w);
                *(short8*)(Bsh + ((size_t)n * KUH + (uu ^ (n & 7))) * 16) = val;
            }
        }
        __syncthreads();
        #pragma unroll
        for (int kcl = 0; kcl < KC / 2; kcl++) {
            int uA = (kh * (KC / 2) + kcl) * 4 + quad;
            int uB = kcl * 4 + quad;
            short8 bf[NI];
            #pragma unroll
            for (int ni = 0; ni < NI; ni++) {
                int n = w * NW + ni * 16 + colL;
                bf[ni] = *(const short8*)(Bsh + ((size_t)n * KUH + (uB ^ (n & 7))) * 16);
            }
            #pragma unroll
            for (int mi = 0; mi < 4; mi++) {
                int m = mi * 16 + colL;
                short8 af = *(const short8*)(Ash + ((size_t)m * KU + (uA ^ (m & 7))) * 16);
                #pragma unroll
                for (int ni = 0; ni < NI; ni++)
                    acc[mi][ni] = __builtin_amdgcn_mfma_f32_16x16x32_bf16(af, bf[ni], acc[mi][ni], 0, 0, 0);
            }
        }
    }
    __syncthreads();   // all LDS reads done; Csh/scsh overlay safe

    // ---- attention scores ----
    float asv[NI], adv[NI];
    #pragma unroll
    for (int ni = 0; ni < NI; ni++) {
        int na = (NH == 4) ? (w * 64 + ni * 16 + colL) : (w * 16 + colL);
        asv[ni] = atts[na];
        adv[ni] = attd[na];
    }
    #pragma unroll
    for (int mi = 0; mi < 4; mi++) {
        float ps[4] = {0.f, 0.f, 0.f, 0.f}, pd[4] = {0.f, 0.f, 0.f, 0.f};
        #pragma unroll
        for (int ni = 0; ni < NI; ni++)
            #pragma unroll
            for (int r = 0; r < 4; r++) {
                ps[r] += acc[mi][ni][r] * asv[ni];
                pd[r] += acc[mi][ni][r] * adv[ni];
            }
        #pragma unroll
        for (int off = 1; off < 16; off <<= 1)
            #pragma unroll
            for (int r = 0; r < 4; r++) {
                ps[r] += __shfl_xor(ps[r], off);
                pd[r] += __shfl_xor(pd[r], off);
            }
        if (colL == 0) {
            #pragma unroll
            for (int r = 0; r < 4; r++) {
                int rloc = mi * 16 + quad * 4 + r;
                if (NH == 4) {
                    int row = m0 + rloc;
                    if (row < M) {
                        as_[(size_t)row * 4 + w] = ps[r];
                        ad_[(size_t)row * 4 + w] = pd[r];
                    }
                } else {
                    scsh[(w * 64 + rloc) * 2 + 0] = ps[r];
                    scsh[(w * 64 + rloc) * 2 + 1] = pd[r];
                }
            }
        }
    }

    // ---- C repack to LDS (bf16) ----
    #pragma unroll
    for (int mi = 0; mi < 4; mi++)
        #pragma unroll
        for (int ni = 0; ni < NI; ni++)
            #pragma unroll
            for (int r = 0; r < 4; r++)
                Csh[(size_t)(mi * 16 + quad * 4 + r) * (N + 8) + w * NW + ni * 16 + colL] =
                    f2bf(acc[mi][ni][r]);
    __syncthreads();

    // ---- coalesced global store ----
    {
        constexpr int CNT = 64 * (N / 8) / 256;
        #pragma unroll
        for (int i = 0; i < CNT; i++) {
            int v = t + 256 * i;
            int m = v / (N / 8), u = v % (N / 8);
            int row = m0 + m;
            if (row < M)
                *(short8*)(C + (size_t)row * N + u * 8) =
                    *(const short8*)(Csh + (size_t)m * (N + 8) + u * 8);
        }
    }
    if (NH == 1 && t < 64) {
        int row = m0 + t;
        if (row < M) {
            float s = 0.f, d = 0.f;
            #pragma unroll
            for (int ww = 0; ww < 4; ww++) {
                s += scsh[(ww * 64 + t) * 2 + 0];
                d += scsh[(ww * 64 + t) * 2 + 1];
            }
            as_[row] = s;
            ad_[row] = d;
        }
    }
}

// standalone GEMM (layer 2)
template<int K, int N, int NH, bool A_BF16>
__global__ __launch_bounds__(256) void k_gemm_mfma(
    const void* __restrict__ Aptr, const float* __restrict__ W,
    const float* __restrict__ atts, const float* __restrict__ attd,
    unsigned short* __restrict__ C, float* __restrict__ as_, float* __restrict__ ad_,
    int M)
{
    gemm_body<K, N, NH, A_BF16>(blockIdx.x, Aptr, W, atts, attd, C, as_, ad_, M);
}

// fused: GEMM1 blocks striped 1-in-5 with CSR-scatter blocks (co-schedule MFMA + VMEM latency)
__global__ __launch_bounds__(256) void k_gemm1_scatter(
    const void* __restrict__ Aptr, const float* __restrict__ W,
    const float* __restrict__ atts, const float* __restrict__ attd,
    unsigned short* __restrict__ C, float* __restrict__ as_, float* __restrict__ ad_,
    int M,
    const int* __restrict__ src, const int* __restrict__ dst,
    int* __restrict__ writeptr, int* __restrict__ csr)
{
    int bid = blockIdx.x;
    int g = bid / 5, r = bid % 5;
    if (r == 0 && g < GB1) {
        gemm_body<128, 256, 4, false>(g, Aptr, W, atts, attd, C, as_, ad_, M);
    } else {
        int ng = (r == 0) ? g : g + 1;           // # gemm blocks with index < bid
        if (ng > GB1) ng = GB1;
        int sb = bid - ng;                        // scatter ordinal
        int i = sb * 256 + threadIdx.x;
        if (i < EE) {
            int pos = atomicAdd(&writeptr[dst[i]], 1);
            csr[pos] = src[i];
        }
    }
}

// ---------------- Layer-1 aggregation: wave/node, half-wave/edge, inline e-score ----------------
__global__ __launch_bounds__(256) void k_l1_agg(
    const unsigned short* __restrict__ xt1, const float* __restrict__ as1,
    const float* __restrict__ ad1, const int* __restrict__ rowptr,
    const int* __restrict__ csr, const float* __restrict__ b1,
    unsigned short* __restrict__ h1)
{
    int t = threadIdx.x;
    int lane = t & 63, w = t >> 6;
    int n = blockIdx.x * 4 + w;
    int beg = rowptr[n], deg = rowptr[n + 1] - beg;
    int half = lane >> 5, c = lane & 31, h = c >> 3;  // lane owns channels 8c..8c+7
    float adh = ad1[n * 4 + h];

    float acc[8] = {0.f, 0.f, 0.f, 0.f, 0.f, 0.f, 0.f, 0.f};
    float esum = 0.f;
    int j = 0;
    for (; j + 4 <= deg; j += 4) {
        int p = beg + j + half * 2;
        int s0 = csr[p], s1 = csr[p + 1];
        float e0 = __expf(lrelu(as1[s0 * 4 + h] + adh));
        float e1 = __expf(lrelu(as1[s1 * 4 + h] + adh));
        short8 r0 = *(const short8*)(xt1 + (size_t)s0 * 256 + c * 8);
        short8 r1 = *(const short8*)(xt1 + (size_t)s1 * 256 + c * 8);
        esum += e0 + e1;
        #pragma unroll
        for (int k = 0; k < 8; k++)
            acc[k] += bf2f((unsigned short)r0[k]) * e0 + bf2f((unsigned short)r1[k]) * e1;
    }
    for (; j < deg; j += 2) {
        int jj = j + half;
        if (jj < deg) {
            int p = beg + jj;
            int s = csr[p];
            float e = __expf(lrelu(as1[s * 4 + h] + adh));
            short8 r = *(const short8*)(xt1 + (size_t)s * 256 + c * 8);
            esum += e;
            #pragma unroll
            for (int k = 0; k < 8; k++) acc[k] += bf2f((unsigned short)r[k]) * e;
        }
    }
    #pragma unroll
    for (int k = 0; k < 8; k++) acc[k] += __shfl_xor(acc[k], 32);
    esum += __shfl_xor(esum, 32);
    if (half == 0) {
        float rs = 1.f / (esum + 1e-16f);
        float4 bl = *(const float4*)(b1 + c * 8);
        float4 bh = *(const float4*)(b1 + c * 8 + 4);
        float bb[8] = {bl.x, bl.y, bl.z, bl.w, bh.x, bh.y, bh.z, bh.w};
        short8 o;
        #pragma unroll
        for (int k = 0; k < 8; k++)
            o[k] = (short)f2bf(fmaxf(acc[k] * rs + bb[k], 0.f));
        *(short8*)(h1 + (size_t)n * 256 + c * 8) = o;
    }
}

// ---------------- Layer-2 aggregation + fc + sigmoid: wave/node, inline e-score ----------------
__global__ __launch_bounds__(256) void k_l2_agg(
    const unsigned short* __restrict__ xt2, const float* __restrict__ as2,
    const float* __restrict__ ad2, const int* __restrict__ rowptr,
    const int* __restrict__ csr, const float* __restrict__ b2,
    const float* __restrict__ fcw, const float* __restrict__ fcb,
    float* __restrict__ out)
{
    int t = threadIdx.x;
    int lane = t & 63, w = t >> 6;
    int n = blockIdx.x * 4 + w;
    int beg = rowptr[n], deg = rowptr[n + 1] - beg;
    int half = lane >> 5, c = lane & 31;   // lane owns channels 2c, 2c+1
    float adv = ad2[n];

    float a0 = 0.f, a1 = 0.f, esum = 0.f;
    int j = 0;
    for (; j + 4 <= deg; j += 4) {
        int p = beg + j + half * 2;
        int s0 = csr[p], s1 = csr[p + 1];
        float e0 = __expf(lrelu(as2[s0] + adv));
        float e1 = __expf(lrelu(as2[s1] + adv));
        unsigned int r0 = *(const unsigned int*)(xt2 + (size_t)s0 * 64 + c * 2);
        unsigned int r1 = *(const unsigned int*)(xt2 + (size_t)s1 * 64 + c * 2);
        esum += e0 + e1;
        a0 += bf2f(r0 & 0xffff) * e0 + bf2f(r1 & 0xffff) * e1;
        a1 += bf2f(r0 >> 16) * e0 + bf2f(r1 >> 16) * e1;
    }
    for (; j < deg; j += 2) {
        int jj = j + half;
        if (jj < deg) {
            int p = beg + jj;
            int s = csr[p];
            float e = __expf(lrelu(as2[s] + adv));
            unsigned int r = *(const unsigned int*)(xt2 + (size_t)s * 64 + c * 2);
            esum += e;
            a0 += bf2f(r & 0xffff) * e;
            a1 += bf2f(r >> 16) * e;
        }
    }
    a0 += __shfl_xor(a0, 32);
    a1 += __shfl_xor(a1, 32);
    esum += __shfl_xor(esum, 32);
    if (half == 0) {
        float rs = 1.f / (esum + 1e-16f);
        float o0 = fmaxf(a0 * rs + b2[c * 2], 0.f);
        float o1 = fmaxf(a1 * rs + b2[c * 2 + 1], 0.f);
        float z = o0 * fcw[c * 2] + o1 * fcw[c * 2 + 1];
        #pragma unroll
        for (int off = 16; off; off >>= 1) z += __shfl_xor(z, off);
        if (c == 0) out[n] = 1.f / (1.f + __expf(-(z + fcb[0])));
    }
}

// ---------------- launch ----------------

extern "C" void kernel_launch(void* const* d_in, const int* in_sizes, int n_in,
                              void* d_out, int out_size, void* d_ws, size_t ws_size,
                              hipStream_t stream) {
    const float* x    = (const float*)d_in[0];
    const int*   ei   = (const int*)d_in[1];
    const float* W1   = (const float*)d_in[2];
    const float* as1w = (const float*)d_in[3];
    const float* ad1w = (const float*)d_in[4];
    const float* b1   = (const float*)d_in[5];
    const float* W2   = (const float*)d_in[6];
    const float* as2w = (const float*)d_in[7];
    const float* ad2w = (const float*)d_in[8];
    const float* b2   = (const float*)d_in[9];
    const float* fcw  = (const float*)d_in[10];
    const float* fcb  = (const float*)d_in[11];
    float* out = (float*)d_out;

    const int* src = ei;
    const int* dst = ei + EE;

    char* base = (char*)d_ws;
    size_t off = 0;
    auto alloc = [&](size_t bytes) -> void* {
        void* p = base + off;
        off = (off + bytes + 255) & ~(size_t)255;
        return p;
    };
    int*   rowptr   = (int*)alloc((NN + 1) * sizeof(int));
    int*   cnt      = (int*)alloc(NN * sizeof(int));
    int*   tmp      = (int*)alloc(NN * sizeof(int));
    int*   bsum     = (int*)alloc(SG * sizeof(int));
    int*   boff     = (int*)alloc(SG * sizeof(int));
    int*   writeptr = (int*)alloc(NN * sizeof(int));
    int*   csr      = (int*)alloc(ET * sizeof(int));
    unsigned short* xt1 = (unsigned short*)alloc((size_t)NN * 256 * sizeof(unsigned short));
    unsigned short* h1  = (unsigned short*)alloc((size_t)NN * 256 * sizeof(unsigned short));
    float* as1      = (float*)alloc(NN * 4 * sizeof(float));
    float* ad1      = (float*)alloc(NN * 4 * sizeof(float));
    float* as2      = (float*)alloc(NN * sizeof(float));
    float* ad2      = (float*)alloc(NN * sizeof(float));
    unsigned short* xt2 = xt1;   // xt1 dead after l1_agg; reuse

    // CSR build (cnt=0 via memset; self-loops folded into scan arithmetic)
    hipMemsetAsync(cnt, 0, NN * sizeof(int), stream);
    k_hist<<<(EE + 255) / 256, 256, 0, stream>>>(dst, cnt);
    k_scan1<<<SG, 256, 0, stream>>>(cnt, tmp, bsum);
    k_scan2<<<1, 256, 0, stream>>>(bsum, boff);
    k_scan3_prep<<<SG, 256, 0, stream>>>(tmp, boff, rowptr, writeptr, csr);

    // GEMM1 (MFMA) striped with scatter (VMEM-latency) in one heterogeneous launch
    int fused_blocks = GB1 + (EE + 255) / 256;   // 782 + 3125 = 3907
    k_gemm1_scatter<<<fused_blocks, 256, 0, stream>>>(
        x, W1, as1w, ad1w, xt1, as1, ad1, NN, src, dst, writeptr, csr);

    k_l1_agg<<<(NN + 3) / 4, 256, 0, stream>>>(xt1, as1, ad1, rowptr, csr, b1, h1);
    k_gemm_mfma<256, 64, 1, true><<<GB1, 256, 0, stream>>>(
        h1, W2, as2w, ad2w, xt2, as2, ad2, NN);
    k_l2_agg<<<(NN + 3) / 4, 256, 0, stream>>>(xt2, as2, ad2, rowptr, csr, b2, fcw, fcb, out);
}